// Round 4
// baseline (1178.551 us; speedup 1.0000x reference)
//
#include <hip/hip_runtime.h>
#include <cstdint>

typedef unsigned short u16;
typedef unsigned int u32;
typedef __attribute__((ext_vector_type(8))) short short8;   // 8 bf16 (MFMA A/B frag)
typedef __attribute__((ext_vector_type(4))) float floatx4;  // MFMA C/D frag

__device__ __forceinline__ float b2f(u16 u) {
    union { unsigned int i; float f; } c; c.i = ((unsigned int)u) << 16; return c.f;
}
__device__ __forceinline__ u16 f2b(float f) {
    union { float f; unsigned int i; } c; c.f = f;
    unsigned int u = c.i;
    u = u + 0x7FFFu + ((u >> 16) & 1u);   // RNE
    return (u16)(u >> 16);
}
__device__ __forceinline__ float u2f(u32 u) { union { u32 u; float f; } c; c.u = u; return c.f; }

// ---------------------------------------------------------------------------
// Fused Q/K/V projection GEMM. Y[m,n] = sum_k x[m,k]*W[n,k] + bias[n].
// grid (32, 24): which = blockIdx.y>>3 (0=q fp32, 1=k bf16, 2=v -> vt hi/lo bf16 transposed).
// ---------------------------------------------------------------------------
__global__ __launch_bounds__(256) void gemm_qkv(
    const float* __restrict__ x,
    const float* __restrict__ Wq, const float* __restrict__ Wk, const float* __restrict__ Wv,
    const float* __restrict__ bq, const float* __restrict__ bk, const float* __restrict__ bv,
    float* __restrict__ qout, u16* __restrict__ kout,
    u16* __restrict__ vthi, u16* __restrict__ vtlo)
{
    __shared__ u16 xs[64 * 72];
    __shared__ u16 wsl[64 * 72];
    int tid = threadIdx.x;
    int lane = tid & 63;
    int wv = tid >> 6;
    int lo = lane & 15, hi = lane >> 4;
    int which = blockIdx.y >> 3;
    int m0 = blockIdx.x * 64, n0 = (blockIdx.y & 7) * 64;
    const float* W    = which == 0 ? Wq : (which == 1 ? Wk : Wv);
    const float* bias = which == 0 ? bq : (which == 1 ? bk : bv);

    floatx4 acc[4];
#pragma unroll
    for (int mt = 0; mt < 4; ++mt) acc[mt] = (floatx4){0.f, 0.f, 0.f, 0.f};

    for (int k0 = 0; k0 < 512; k0 += 64) {
        __syncthreads();
#pragma unroll
        for (int i = 0; i < 2; ++i) {
            int v = tid + i * 256;
            int row = v >> 3, c8 = (v & 7) * 8;
            const float* ap = x + (m0 + row) * 512 + k0 + c8;
            const float* wp = W + (n0 + row) * 512 + k0 + c8;
            float4 a0 = *(const float4*)(ap);
            float4 a1 = *(const float4*)(ap + 4);
            float4 w0 = *(const float4*)(wp);
            float4 w1v = *(const float4*)(wp + 4);
            union { u16 u[8]; uint4 q; } ca, cw;
            ca.u[0] = f2b(a0.x); ca.u[1] = f2b(a0.y); ca.u[2] = f2b(a0.z); ca.u[3] = f2b(a0.w);
            ca.u[4] = f2b(a1.x); ca.u[5] = f2b(a1.y); ca.u[6] = f2b(a1.z); ca.u[7] = f2b(a1.w);
            cw.u[0] = f2b(w0.x); cw.u[1] = f2b(w0.y); cw.u[2] = f2b(w0.z); cw.u[3] = f2b(w0.w);
            cw.u[4] = f2b(w1v.x); cw.u[5] = f2b(w1v.y); cw.u[6] = f2b(w1v.z); cw.u[7] = f2b(w1v.w);
            *(uint4*)(xs + row * 72 + c8)  = ca.q;
            *(uint4*)(wsl + row * 72 + c8) = cw.q;
        }
        __syncthreads();
#pragma unroll
        for (int ks = 0; ks < 2; ++ks) {
            short8 bfr = *(const short8*)(wsl + (wv * 16 + lo) * 72 + ks * 32 + hi * 8);
#pragma unroll
            for (int mt = 0; mt < 4; ++mt) {
                short8 afr = *(const short8*)(xs + (mt * 16 + lo) * 72 + ks * 32 + hi * 8);
                acc[mt] = __builtin_amdgcn_mfma_f32_16x16x32_bf16(afr, bfr, acc[mt], 0, 0, 0);
            }
        }
    }

    int n = n0 + wv * 16 + lo;
    float bv2 = bias[n];
    if (which == 2) {
        // transpose V tile through LDS; emit vt_hi/vt_lo bf16 [bh][d][c]
        __syncthreads();                           // xs/wsl reuse: all waves done with MFMAs
        int nl = wv * 16 + lo;                     // local d
#pragma unroll
        for (int mt = 0; mt < 4; ++mt)
#pragma unroll
            for (int r = 0; r < 4; ++r) {
                int ml = mt * 16 + hi * 4 + r;     // local c
                float y = acc[mt][r] + bv2;
                u16 vh = f2b(y);
                u16 vl = f2b(y - b2f(vh));
                xs[nl * 72 + ml]  = vh;
                wsl[nl * 72 + ml] = vl;
            }
        __syncthreads();
        int row = tid >> 2, seg = (tid & 3) * 16;  // row = local d, seg = local c chunk
        int b = m0 >> 10, c0 = m0 & 1023, h2 = n0 >> 6;
        size_t dst = ((size_t)((b * 8 + h2) * 64 + row)) * 1024 + c0 + seg;
        *(uint4*)(vthi + dst)     = *(uint4*)(xs  + row * 72 + seg);
        *(uint4*)(vthi + dst + 8) = *(uint4*)(xs  + row * 72 + seg + 8);
        *(uint4*)(vtlo + dst)     = *(uint4*)(wsl + row * 72 + seg);
        *(uint4*)(vtlo + dst + 8) = *(uint4*)(wsl + row * 72 + seg + 8);
    } else {
        int h = n >> 6, dd = n & 63;
#pragma unroll
        for (int mt = 0; mt < 4; ++mt)
#pragma unroll
            for (int r = 0; r < 4; ++r) {
                int m = m0 + mt * 16 + hi * 4 + r;  // C/D: row=(lane>>4)*4+reg, col=lane&15
                float y = acc[mt][r] + bv2;
                int b = m >> 10, c = m & 1023;
                int idx = (((b * 8 + h) * 1024) + c) * 64 + dd;
                if (which == 0) qout[idx] = y;
                else            kout[idx] = f2b(y);
            }
    }
}

// ---------------------------------------------------------------------------
// Output GEMM: Y[m,n] = sum_k A[m,k]*Wo[n,k] + bo[n], fp32 out, [m*512+n].
// ---------------------------------------------------------------------------
__global__ __launch_bounds__(256) void gemm_out(
    const float* __restrict__ A, const float* __restrict__ W, const float* __restrict__ bias,
    float* __restrict__ outf)
{
    __shared__ u16 xs[64 * 72];
    __shared__ u16 wsl[64 * 72];
    int tid = threadIdx.x;
    int lane = tid & 63;
    int wv = tid >> 6;
    int lo = lane & 15, hi = lane >> 4;
    int m0 = blockIdx.x * 64, n0 = blockIdx.y * 64;

    floatx4 acc[4];
#pragma unroll
    for (int mt = 0; mt < 4; ++mt) acc[mt] = (floatx4){0.f, 0.f, 0.f, 0.f};

    for (int k0 = 0; k0 < 512; k0 += 64) {
        __syncthreads();
#pragma unroll
        for (int i = 0; i < 2; ++i) {
            int v = tid + i * 256;
            int row = v >> 3, c8 = (v & 7) * 8;
            const float* ap = A + (m0 + row) * 512 + k0 + c8;
            const float* wp = W + (n0 + row) * 512 + k0 + c8;
            float4 a0 = *(const float4*)(ap);
            float4 a1 = *(const float4*)(ap + 4);
            float4 w0 = *(const float4*)(wp);
            float4 w1v = *(const float4*)(wp + 4);
            union { u16 u[8]; uint4 q; } ca, cw;
            ca.u[0] = f2b(a0.x); ca.u[1] = f2b(a0.y); ca.u[2] = f2b(a0.z); ca.u[3] = f2b(a0.w);
            ca.u[4] = f2b(a1.x); ca.u[5] = f2b(a1.y); ca.u[6] = f2b(a1.z); ca.u[7] = f2b(a1.w);
            cw.u[0] = f2b(w0.x); cw.u[1] = f2b(w0.y); cw.u[2] = f2b(w0.z); cw.u[3] = f2b(w0.w);
            cw.u[4] = f2b(w1v.x); cw.u[5] = f2b(w1v.y); cw.u[6] = f2b(w1v.z); cw.u[7] = f2b(w1v.w);
            *(uint4*)(xs + row * 72 + c8)  = ca.q;
            *(uint4*)(wsl + row * 72 + c8) = cw.q;
        }
        __syncthreads();
#pragma unroll
        for (int ks = 0; ks < 2; ++ks) {
            short8 bfr = *(const short8*)(wsl + (wv * 16 + lo) * 72 + ks * 32 + hi * 8);
#pragma unroll
            for (int mt = 0; mt < 4; ++mt) {
                short8 afr = *(const short8*)(xs + (mt * 16 + lo) * 72 + ks * 32 + hi * 8);
                acc[mt] = __builtin_amdgcn_mfma_f32_16x16x32_bf16(afr, bfr, acc[mt], 0, 0, 0);
            }
        }
    }

    int n = n0 + wv * 16 + lo;
    float bv = bias[n];
#pragma unroll
    for (int mt = 0; mt < 4; ++mt)
#pragma unroll
        for (int r = 0; r < 4; ++r) {
            int m = m0 + mt * 16 + hi * 4 + r;
            outf[m * 512 + n] = acc[mt][r] + bv;
        }
}

// ---------------------------------------------------------------------------
// Fused second-order attention, v16 = v15 with the P-packing done via the
// v14-verified f2b (RNE) instead of inline-asm v_cvt_pk_bf16_f32 (v15's only
// unverified semantic assumption; suspected halves-swap caused absmax 0.31).
// Structure: P exchange GROUPED over 4 chunks (128 keys) -> barriers 32 -> 8;
// between barriers each wave runs a long independent MFMA+scoring stream
// (chunk tail for 3 of 4 chunks is just 4 shfl + 2 exp2 + pack -- no LDS,
// no barrier, no vmcnt(0) drain). All 64 lanes publish (lane's hi selects
// which stashed chunk; values are hi-duplicated after the xor16/32 reduce).
// LDS plane stride 528 u16 so planes don't bank-alias. Per-block j0 phase
// offset desyncs stall phases across co-resident blocks (sum order invariant).
// ---------------------------------------------------------------------------
__global__ __launch_bounds__(256, 4) void attn16(
    const float* __restrict__ qf, const u16* __restrict__ kb,
    const u16* __restrict__ vthi, const u16* __restrict__ vtlo,
    const float* __restrict__ w1, const float* __restrict__ b1, const float* __restrict__ w2,
    float* __restrict__ ao)
{
    __shared__ float q_l[4 * 64];
    __shared__ __align__(16) u16 plds[2 * 4 * 528];   // [dbuf][chunk plane 528][A-frag order]
    __shared__ float l_sh[4];
    int tid = threadIdx.x;
    int lane = tid & 63;
    int wv = tid >> 6;
    int lo = lane & 15, hi = lane >> 4;
    int bh = blockIdx.x >> 8;                      // 0..15 = b*8+h
    int qbase = (blockIdx.x & 255) << 2;           // block's first query
    int qi = qbase | wv;                           // this wave's query
    int joff = ((blockIdx.x & 31) << 5);           // per-block key phase offset (0..992)

    const float NA = -2.45546696f;                 // -1.702 * log2(e)

    // zero p-LDS once: A-frag rows q=4..15 must stay 0 so PV C rows 4..15 are clean
    for (int i = tid; i < (2 * 4 * 528) / 2; i += 256) ((u32*)plds)[i] = 0;

    q_l[wv * 64 + lane] = qf[(bh * 1024 + qi) * 64 + lane];

    // qp[e]+b1[e] at lane=e
    float qpacc = b1[lane];
#pragma unroll
    for (int d8 = 0; d8 < 64; d8 += 8) {
        float4 wa = *(const float4*)(w1 + lane * 192 + d8);
        float4 wb = *(const float4*)(w1 + lane * 192 + d8 + 4);
        const float* q8 = q_l + wv * 64 + d8;      // wave-uniform broadcast reads
        qpacc = __builtin_fmaf(q8[0], wa.x, qpacc);
        qpacc = __builtin_fmaf(q8[1], wa.y, qpacc);
        qpacc = __builtin_fmaf(q8[2], wa.z, qpacc);
        qpacc = __builtin_fmaf(q8[3], wa.w, qpacc);
        qpacc = __builtin_fmaf(q8[4], wb.x, qpacc);
        qpacc = __builtin_fmaf(q8[5], wb.y, qpacc);
        qpacc = __builtin_fmaf(q8[6], wb.z, qpacc);
        qpacc = __builtin_fmaf(q8[7], wb.w, qpacc);
    }
    qpacc *= NA;                                   // qp' = c * (qp + b1)

    // w2c packed: wc' = w2[e] * (1/8)*log2e / c = w2[e] * -0.07344288
    u32 wcp[4][2];
    float w2row = w2[lane] * -0.07344288f;
#pragma unroll
    for (int mt = 0; mt < 4; ++mt)
#pragma unroll
        for (int h2 = 0; h2 < 2; ++h2) {
            int e0 = mt * 16 + hi * 4 + h2 * 2;
            u32 lo16 = (u32)f2b(__shfl(w2row, e0));
            u32 hi16 = (u32)f2b(__shfl(w2row, e0 + 1));
            wcp[mt][h2] = (hi16 << 16) | lo16;
        }

    // q pieces for frag build: qv2[ks][j] = q[ks*32 + hi*8 + j]
    float qv2[2][8];
#pragma unroll
    for (int ks = 0; ks < 2; ++ks)
#pragma unroll
        for (int j = 0; j < 8; ++j)
            qv2[ks][j] = q_l[wv * 64 + ks * 32 + hi * 8 + j];

    // A-frags: c * qw'[e = mt*16+lo][dd = ks*32 + hi*8 + j], bf16
    short8 af[4][2];
#pragma unroll
    for (int mt = 0; mt < 4; ++mt) {
        const float* wr = w1 + (mt * 16 + lo) * 192;
#pragma unroll
        for (int ks = 0; ks < 2; ++ks) {
            int dd0 = ks * 32 + hi * 8;
            float4 a0 = *(const float4*)(wr + 128 + dd0);
            float4 a1 = *(const float4*)(wr + 128 + dd0 + 4);
            float4 k0 = *(const float4*)(wr + 64 + dd0);
            float4 k1 = *(const float4*)(wr + 64 + dd0 + 4);
            union { u16 u[8]; short8 s; } cv;
            cv.u[0] = f2b(NA * __builtin_fmaf(qv2[ks][0], a0.x, k0.x));
            cv.u[1] = f2b(NA * __builtin_fmaf(qv2[ks][1], a0.y, k0.y));
            cv.u[2] = f2b(NA * __builtin_fmaf(qv2[ks][2], a0.z, k0.z));
            cv.u[3] = f2b(NA * __builtin_fmaf(qv2[ks][3], a0.w, k0.w));
            cv.u[4] = f2b(NA * __builtin_fmaf(qv2[ks][4], a1.x, k1.x));
            cv.u[5] = f2b(NA * __builtin_fmaf(qv2[ks][5], a1.y, k1.y));
            cv.u[6] = f2b(NA * __builtin_fmaf(qv2[ks][6], a1.z, k1.z));
            cv.u[7] = f2b(NA * __builtin_fmaf(qv2[ks][7], a1.w, k1.w));
            af[mt][ks] = cv.s;
        }
    }

    // rank-1 qp' C-init, loop-invariant
    floatx4 qpinit[4];
    {
        const floatx4 z = (floatx4){0.f, 0.f, 0.f, 0.f};
        union { u16 u[8]; short8 s; } bb;
#pragma unroll
        for (int i = 0; i < 8; ++i) bb.u[i] = 0;
        bb.u[0] = (hi == 0) ? (u16)0x3F80 : (u16)0;   // bf16 1.0 at k=0
#pragma unroll
        for (int mt = 0; mt < 4; ++mt) {
            float qpv = __shfl(qpacc, mt * 16 + lo);
            union { u16 u[8]; short8 s; } aa;
#pragma unroll
            for (int i = 0; i < 8; ++i) aa.u[i] = 0;
            aa.u[0] = (hi == 0) ? f2b(qpv) : (u16)0;
            qpinit[mt] = __builtin_amdgcn_mfma_f32_16x16x32_bf16(aa.s, bb.s, z, 0, 0, 0);
        }
    }

    // zero-init must complete block-wide before any wave's first p-write
    __syncthreads();

    float l_run = 0.f;
    floatx4 pvacc = (floatx4){0.f, 0.f, 0.f, 0.f};   // out[q=row 0..3][d = wv*16+col]
    const u16* kbase = kb + bh * 65536;
    // V^T B-frag bases: this wave's d-tile row = wv*16+lo, k-offset hi*8
    const u16* vhb = vthi + bh * 65536 + (wv * 16 + lo) * 1024 + hi * 8;
    const u16* vlb = vtlo + bh * 65536 + (wv * 16 + lo) * 1024 + hi * 8;

    // prologue: load B-frags for the first chunk (key base joff)
    short8 bf[2][2];
#pragma unroll
    for (int t = 0; t < 2; ++t)
#pragma unroll
        for (int ks = 0; ks < 2; ++ks) {
            uint4 kv = *(const uint4*)(kbase + (joff + t * 16 + lo) * 64 + ks * 32 + hi * 8);
            bf[t][ks] = *(short8*)&kv;
        }

    for (int g = 0; g < 8; ++g) {
        u32 st0 = 0, st1 = 0, st2 = 0, st3 = 0;
#pragma unroll
        for (int c = 0; c < 4; ++c) {
            int jc = (g * 128 + c * 32 + joff) & 1023;   // this chunk's key base (bf holds it)
            int jn = (jc + 32) & 1023;                   // next chunk to prefetch

            float s0a = 0.f, s0b = 0.f, s1a = 0.f, s1b = 0.f;

            // pipeline prologue: mt=0's 4 MFMAs
            floatx4 aP[2], aN[2];
            aP[0] = __builtin_amdgcn_mfma_f32_16x16x32_bf16(af[0][0], bf[0][0], qpinit[0], 0, 0, 0);
            aP[0] = __builtin_amdgcn_mfma_f32_16x16x32_bf16(af[0][1], bf[0][1], aP[0], 0, 0, 0);
            aP[1] = __builtin_amdgcn_mfma_f32_16x16x32_bf16(af[0][0], bf[1][0], qpinit[0], 0, 0, 0);
            aP[1] = __builtin_amdgcn_mfma_f32_16x16x32_bf16(af[0][1], bf[1][1], aP[1], 0, 0, 0);

#pragma unroll
            for (int mt = 0; mt < 4; ++mt) {
                if (mt < 3) {
                    aN[0] = __builtin_amdgcn_mfma_f32_16x16x32_bf16(af[mt + 1][0], bf[0][0], qpinit[mt + 1], 0, 0, 0);
                    aN[0] = __builtin_amdgcn_mfma_f32_16x16x32_bf16(af[mt + 1][1], bf[0][1], aN[0], 0, 0, 0);
                    aN[1] = __builtin_amdgcn_mfma_f32_16x16x32_bf16(af[mt + 1][0], bf[1][0], qpinit[mt + 1], 0, 0, 0);
                    aN[1] = __builtin_amdgcn_mfma_f32_16x16x32_bf16(af[mt + 1][1], bf[1][1], aN[1], 0, 0, 0);
                } else {
                    // reload K frags in place for the next chunk
#pragma unroll
                    for (int t = 0; t < 2; ++t)
#pragma unroll
                        for (int ks = 0; ks < 2; ++ks) {
                            uint4 kv = *(const uint4*)(kbase + (jn + t * 16 + lo) * 64 + ks * 32 + hi * 8);
                            bf[t][ks] = *(short8*)&kv;
                        }
                }

                // score mt's pair: acc IS x' = c*hid; sigma via pair-merged rcp
#pragma unroll
                for (int h2 = 0; h2 < 2; ++h2) {
                    u32 wp = wcp[mt][h2];
                    float w0 = u2f(wp << 16);
                    float w1v = u2f(wp & 0xFFFF0000u);
#pragma unroll
                    for (int t = 0; t < 2; ++t) {
                        float x0 = aP[t][h2 * 2 + 0];
                        float x1 = aP[t][h2 * 2 + 1];
                        float a0 = 1.0f + __builtin_amdgcn_exp2f(x0);
                        float a1 = 1.0f + __builtin_amdgcn_exp2f(x1);
                        float rc = __builtin_amdgcn_rcpf(a0 * a1);
                        if (t == 0) {
                            s0a = __builtin_fmaf(x0 * w0,  rc * a1, s0a);
                            s0b = __builtin_fmaf(x1 * w1v, rc * a0, s0b);
                        } else {
                            s1a = __builtin_fmaf(x0 * w0,  rc * a1, s1a);
                            s1b = __builtin_fmaf(x1 * w1v, rc * a0, s1b);
                        }
                    }
                }
                aP[0] = aN[0];
                aP[1] = aN[1];
            }

            float s0 = s0a + s0b, s1 = s1a + s1b;
            s0 += __shfl_xor(s0, 16); s0 += __shfl_xor(s0, 32);   // s[j=lo] (dup over hi)
            s1 += __shfl_xor(s1, 16); s1 += __shfl_xor(s1, 32);   // s[j=16+lo]

            // fixed-shift softmax numerator (scores bounded, safe)
            float p0 = __builtin_amdgcn_exp2f(s0 - 16.0f);
            float p1 = __builtin_amdgcn_exp2f(s1 - 16.0f);
            u16 ph0 = f2b(p0);                         // verified RNE path (v14)
            u16 ph1 = f2b(p1);
            u32 pk = ((u32)ph1 << 16) | (u32)ph0;      // lo16 = j=lo, hi16 = j=16+lo
            l_run += b2f(ph0) + b2f(ph1);              // l from QUANTIZED p
            if (c == 0) st0 = pk; else if (c == 1) st1 = pk;
            else if (c == 2) st2 = pk; else st3 = pk;
        }

        // group exchange: lane publishes chunk (c = hi)'s pair for its lo
        u16* pw = plds + (g & 1) * (4 * 528);
        u32 sv = (hi == 0) ? st0 : (hi == 1) ? st1 : (hi == 2) ? st2 : st3;
        int wb = hi * 528 + wv * 8 + (lo & 7);
        pw[wb + (lo >> 3) * 128]       = (u16)sv;          // j = lo
        pw[wb + (2 + (lo >> 3)) * 128] = (u16)(sv >> 16);  // j = 16+lo
        __syncthreads();

        // PV on the matrix pipe: out[q][d] += P[q][j] * (Vhi + Vlo)[d][j]
#pragma unroll
        for (int c = 0; c < 4; ++c) {
            int jg = (g * 128 + c * 32 + joff) & 1023;
            uint4 vh = *(const uint4*)(vhb + jg);
            uint4 vl = *(const uint4*)(vlb + jg);
            short8 pf = *(const short8*)(pw + c * 528 + lane * 8);
            pvacc = __builtin_amdgcn_mfma_f32_16x16x32_bf16(pf, *(short8*)&vh, pvacc, 0, 0, 0);
            pvacc = __builtin_amdgcn_mfma_f32_16x16x32_bf16(pf, *(short8*)&vl, pvacc, 0, 0, 0);
        }
    }

    float l = l_run;
    l += __shfl_xor(l, 1); l += __shfl_xor(l, 2);
    l += __shfl_xor(l, 4); l += __shfl_xor(l, 8);
    if (lane == 0) l_sh[wv] = l;
    __syncthreads();

    if (hi == 0) {                                 // C rows 0..3 live on lanes 0..15
        int b = bh >> 3, h = bh & 7;
#pragma unroll
        for (int q = 0; q < 4; ++q) {
            float outv = pvacc[q] * __builtin_amdgcn_rcpf(l_sh[q]);
            ao[((b * 1024 + qbase + q) * 512) + h * 64 + wv * 16 + lo] = outv;
        }
    }
}

// ---------------------------------------------------------------------------
extern "C" void kernel_launch(void* const* d_in, const int* in_sizes, int n_in,
                              void* d_out, int out_size, void* d_ws, size_t ws_size,
                              hipStream_t stream)
{
    (void)in_sizes; (void)n_in; (void)out_size; (void)ws_size;
    const float* x  = (const float*)d_in[0];
    const float* Wq = (const float*)d_in[1];
    const float* bq = (const float*)d_in[2];
    const float* Wk = (const float*)d_in[3];
    const float* bk = (const float*)d_in[4];
    const float* Wv = (const float*)d_in[5];
    const float* bv = (const float*)d_in[6];
    const float* w1 = (const float*)d_in[7];
    const float* b1 = (const float*)d_in[8];
    const float* w2 = (const float*)d_in[9];
    // d_in[10] = b2: scalar shift of all scores -> softmax-invariant -> unused
    const float* Wo = (const float*)d_in[11];
    const float* bo = (const float*)d_in[12];

    char* ws = (char*)d_ws;
    float* q_ws = (float*)(ws);               // 4 MB fp32 (b,h,c,d)
    u16*   k_ws = (u16*)(ws + (4u << 20));    // 2 MB bf16 (b,h,c,d)
    u16*   vthi = (u16*)(ws + (6u << 20));    // 2 MB bf16 V^T hi (b,h,d,c)
    u16*   vtlo = (u16*)(ws + (8u << 20));    // 2 MB bf16 V^T lo (b,h,d,c)
    float* a_ws = (float*)(ws + (10u << 20)); // 4 MB fp32 (b,c,D)

    dim3 blk(256);
    hipLaunchKernelGGL(gemm_qkv, dim3(32, 24), blk, 0, stream,
                       x, Wq, Wk, Wv, bq, bk, bv, q_ws, k_ws, vthi, vtlo);
    hipLaunchKernelGGL(attn16, dim3(4096), blk, 0, stream,
                       q_ws, k_ws, vthi, vtlo, w1, b1, w2, a_ws);
    hipLaunchKernelGGL(gemm_out, dim3(32, 8), blk, 0, stream, a_ws, Wo, bo, (float*)d_out);
}

// Round 5
// 558.714 us; speedup vs baseline: 2.1094x; 2.1094x over previous
//
#include <hip/hip_runtime.h>
#include <cstdint>

typedef unsigned short u16;
typedef unsigned int u32;
typedef __attribute__((ext_vector_type(8))) short short8;   // 8 bf16 (MFMA A/B frag)
typedef __attribute__((ext_vector_type(4))) float floatx4;  // MFMA C/D frag

__device__ __forceinline__ float b2f(u16 u) {
    union { unsigned int i; float f; } c; c.i = ((unsigned int)u) << 16; return c.f;
}
__device__ __forceinline__ u16 f2b(float f) {
    union { float f; unsigned int i; } c; c.f = f;
    unsigned int u = c.i;
    u = u + 0x7FFFu + ((u >> 16) & 1u);   // RNE
    return (u16)(u >> 16);
}
__device__ __forceinline__ float u2f(u32 u) { union { u32 u; float f; } c; c.u = u; return c.f; }

// ---------------------------------------------------------------------------
// Fused Q/K/V projection GEMM. Y[m,n] = sum_k x[m,k]*W[n,k] + bias[n].
// grid (32, 24): which = blockIdx.y>>3 (0=q fp32, 1=k bf16, 2=v -> vt hi/lo bf16 transposed).
// ---------------------------------------------------------------------------
__global__ __launch_bounds__(256) void gemm_qkv(
    const float* __restrict__ x,
    const float* __restrict__ Wq, const float* __restrict__ Wk, const float* __restrict__ Wv,
    const float* __restrict__ bq, const float* __restrict__ bk, const float* __restrict__ bv,
    float* __restrict__ qout, u16* __restrict__ kout,
    u16* __restrict__ vthi, u16* __restrict__ vtlo)
{
    __shared__ u16 xs[64 * 72];
    __shared__ u16 wsl[64 * 72];
    int tid = threadIdx.x;
    int lane = tid & 63;
    int wv = tid >> 6;
    int lo = lane & 15, hi = lane >> 4;
    int which = blockIdx.y >> 3;
    int m0 = blockIdx.x * 64, n0 = (blockIdx.y & 7) * 64;
    const float* W    = which == 0 ? Wq : (which == 1 ? Wk : Wv);
    const float* bias = which == 0 ? bq : (which == 1 ? bk : bv);

    floatx4 acc[4];
#pragma unroll
    for (int mt = 0; mt < 4; ++mt) acc[mt] = (floatx4){0.f, 0.f, 0.f, 0.f};

    for (int k0 = 0; k0 < 512; k0 += 64) {
        __syncthreads();
#pragma unroll
        for (int i = 0; i < 2; ++i) {
            int v = tid + i * 256;
            int row = v >> 3, c8 = (v & 7) * 8;
            const float* ap = x + (m0 + row) * 512 + k0 + c8;
            const float* wp = W + (n0 + row) * 512 + k0 + c8;
            float4 a0 = *(const float4*)(ap);
            float4 a1 = *(const float4*)(ap + 4);
            float4 w0 = *(const float4*)(wp);
            float4 w1v = *(const float4*)(wp + 4);
            union { u16 u[8]; uint4 q; } ca, cw;
            ca.u[0] = f2b(a0.x); ca.u[1] = f2b(a0.y); ca.u[2] = f2b(a0.z); ca.u[3] = f2b(a0.w);
            ca.u[4] = f2b(a1.x); ca.u[5] = f2b(a1.y); ca.u[6] = f2b(a1.z); ca.u[7] = f2b(a1.w);
            cw.u[0] = f2b(w0.x); cw.u[1] = f2b(w0.y); cw.u[2] = f2b(w0.z); cw.u[3] = f2b(w0.w);
            cw.u[4] = f2b(w1v.x); cw.u[5] = f2b(w1v.y); cw.u[6] = f2b(w1v.z); cw.u[7] = f2b(w1v.w);
            *(uint4*)(xs + row * 72 + c8)  = ca.q;
            *(uint4*)(wsl + row * 72 + c8) = cw.q;
        }
        __syncthreads();
#pragma unroll
        for (int ks = 0; ks < 2; ++ks) {
            short8 bfr = *(const short8*)(wsl + (wv * 16 + lo) * 72 + ks * 32 + hi * 8);
#pragma unroll
            for (int mt = 0; mt < 4; ++mt) {
                short8 afr = *(const short8*)(xs + (mt * 16 + lo) * 72 + ks * 32 + hi * 8);
                acc[mt] = __builtin_amdgcn_mfma_f32_16x16x32_bf16(afr, bfr, acc[mt], 0, 0, 0);
            }
        }
    }

    int n = n0 + wv * 16 + lo;
    float bv2 = bias[n];
    if (which == 2) {
        // transpose V tile through LDS; emit vt_hi/vt_lo bf16 [bh][d][c]
        __syncthreads();                           // xs/wsl reuse: all waves done with MFMAs
        int nl = wv * 16 + lo;                     // local d
#pragma unroll
        for (int mt = 0; mt < 4; ++mt)
#pragma unroll
            for (int r = 0; r < 4; ++r) {
                int ml = mt * 16 + hi * 4 + r;     // local c
                float y = acc[mt][r] + bv2;
                u16 vh = f2b(y);
                u16 vl = f2b(y - b2f(vh));
                xs[nl * 72 + ml]  = vh;
                wsl[nl * 72 + ml] = vl;
            }
        __syncthreads();
        int row = tid >> 2, seg = (tid & 3) * 16;  // row = local d, seg = local c chunk
        int b = m0 >> 10, c0 = m0 & 1023, h2 = n0 >> 6;
        size_t dst = ((size_t)((b * 8 + h2) * 64 + row)) * 1024 + c0 + seg;
        *(uint4*)(vthi + dst)     = *(uint4*)(xs  + row * 72 + seg);
        *(uint4*)(vthi + dst + 8) = *(uint4*)(xs  + row * 72 + seg + 8);
        *(uint4*)(vtlo + dst)     = *(uint4*)(wsl + row * 72 + seg);
        *(uint4*)(vtlo + dst + 8) = *(uint4*)(wsl + row * 72 + seg + 8);
    } else {
        int h = n >> 6, dd = n & 63;
#pragma unroll
        for (int mt = 0; mt < 4; ++mt)
#pragma unroll
            for (int r = 0; r < 4; ++r) {
                int m = m0 + mt * 16 + hi * 4 + r;  // C/D: row=(lane>>4)*4+reg, col=lane&15
                float y = acc[mt][r] + bv2;
                int b = m >> 10, c = m & 1023;
                int idx = (((b * 8 + h) * 1024) + c) * 64 + dd;
                if (which == 0) qout[idx] = y;
                else            kout[idx] = f2b(y);
            }
    }
}

// ---------------------------------------------------------------------------
// Output GEMM: Y[m,n] = sum_k A[m,k]*Wo[n,k] + bo[n], fp32 out, [m*512+n].
// ---------------------------------------------------------------------------
__global__ __launch_bounds__(256) void gemm_out(
    const float* __restrict__ A, const float* __restrict__ W, const float* __restrict__ bias,
    float* __restrict__ outf)
{
    __shared__ u16 xs[64 * 72];
    __shared__ u16 wsl[64 * 72];
    int tid = threadIdx.x;
    int lane = tid & 63;
    int wv = tid >> 6;
    int lo = lane & 15, hi = lane >> 4;
    int m0 = blockIdx.x * 64, n0 = blockIdx.y * 64;

    floatx4 acc[4];
#pragma unroll
    for (int mt = 0; mt < 4; ++mt) acc[mt] = (floatx4){0.f, 0.f, 0.f, 0.f};

    for (int k0 = 0; k0 < 512; k0 += 64) {
        __syncthreads();
#pragma unroll
        for (int i = 0; i < 2; ++i) {
            int v = tid + i * 256;
            int row = v >> 3, c8 = (v & 7) * 8;
            const float* ap = A + (m0 + row) * 512 + k0 + c8;
            const float* wp = W + (n0 + row) * 512 + k0 + c8;
            float4 a0 = *(const float4*)(ap);
            float4 a1 = *(const float4*)(ap + 4);
            float4 w0 = *(const float4*)(wp);
            float4 w1v = *(const float4*)(wp + 4);
            union { u16 u[8]; uint4 q; } ca, cw;
            ca.u[0] = f2b(a0.x); ca.u[1] = f2b(a0.y); ca.u[2] = f2b(a0.z); ca.u[3] = f2b(a0.w);
            ca.u[4] = f2b(a1.x); ca.u[5] = f2b(a1.y); ca.u[6] = f2b(a1.z); ca.u[7] = f2b(a1.w);
            cw.u[0] = f2b(w0.x); cw.u[1] = f2b(w0.y); cw.u[2] = f2b(w0.z); cw.u[3] = f2b(w0.w);
            cw.u[4] = f2b(w1v.x); cw.u[5] = f2b(w1v.y); cw.u[6] = f2b(w1v.z); cw.u[7] = f2b(w1v.w);
            *(uint4*)(xs + row * 72 + c8)  = ca.q;
            *(uint4*)(wsl + row * 72 + c8) = cw.q;
        }
        __syncthreads();
#pragma unroll
        for (int ks = 0; ks < 2; ++ks) {
            short8 bfr = *(const short8*)(wsl + (wv * 16 + lo) * 72 + ks * 32 + hi * 8);
#pragma unroll
            for (int mt = 0; mt < 4; ++mt) {
                short8 afr = *(const short8*)(xs + (mt * 16 + lo) * 72 + ks * 32 + hi * 8);
                acc[mt] = __builtin_amdgcn_mfma_f32_16x16x32_bf16(afr, bfr, acc[mt], 0, 0, 0);
            }
        }
    }

    int n = n0 + wv * 16 + lo;
    float bv = bias[n];
#pragma unroll
    for (int mt = 0; mt < 4; ++mt)
#pragma unroll
        for (int r = 0; r < 4; ++r) {
            int m = m0 + mt * 16 + hi * 4 + r;
            outf[m * 512 + n] = acc[mt][r] + bv;
        }
}

// ---------------------------------------------------------------------------
// Fused second-order attention, v17 = v16 minus the two regressions found by
// PMC post-mortem (FETCH 28MB -> 2.4GB):
//  (1) joff REMOVED -- the per-block key phase offset destroyed the lockstep
//      K/V walk that made co-resident blocks share L2 lines (locality >>
//      scheduler smoothness: 2.4 GB streaming vs 28 MB resident).
//  (2) no VGPR stash -- each chunk ds_writes its two bf16 P-values at score
//      time (v14's verified lanes<16 pattern) into its own 528-stride plane;
//      fire-and-forget, drained by the ONE barrier per 4-chunk group.
// Keeps v15/v16's intended win: barriers 32 -> 8, chunk tails for 3 of 4
// chunks are barrier/LDS-drain-free. Double-buffer safe with 1 barrier/group:
// next write to buffer b is 2 groups later, behind barrier(g+1) which all
// waves reach only after finishing g's reads.
// ---------------------------------------------------------------------------
__global__ __launch_bounds__(256, 4) void attn17(
    const float* __restrict__ qf, const u16* __restrict__ kb,
    const u16* __restrict__ vthi, const u16* __restrict__ vtlo,
    const float* __restrict__ w1, const float* __restrict__ b1, const float* __restrict__ w2,
    float* __restrict__ ao)
{
    __shared__ float q_l[4 * 64];
    __shared__ __align__(16) u16 plds[2 * 4 * 528];   // [dbuf][chunk plane 528][A-frag order]
    __shared__ float l_sh[4];
    int tid = threadIdx.x;
    int lane = tid & 63;
    int wv = tid >> 6;
    int lo = lane & 15, hi = lane >> 4;
    int bh = blockIdx.x >> 8;                      // 0..15 = b*8+h
    int qbase = (blockIdx.x & 255) << 2;           // block's first query
    int qi = qbase | wv;                           // this wave's query

    const float NA = -2.45546696f;                 // -1.702 * log2(e)

    // zero p-LDS once: A-frag rows q=4..15 must stay 0 so PV C rows 4..15 are clean
    for (int i = tid; i < 2112; i += 256) ((u32*)plds)[i] = 0;

    q_l[wv * 64 + lane] = qf[(bh * 1024 + qi) * 64 + lane];

    // qp[e]+b1[e] at lane=e
    float qpacc = b1[lane];
#pragma unroll
    for (int d8 = 0; d8 < 64; d8 += 8) {
        float4 wa = *(const float4*)(w1 + lane * 192 + d8);
        float4 wb = *(const float4*)(w1 + lane * 192 + d8 + 4);
        const float* q8 = q_l + wv * 64 + d8;      // wave-uniform broadcast reads
        qpacc = __builtin_fmaf(q8[0], wa.x, qpacc);
        qpacc = __builtin_fmaf(q8[1], wa.y, qpacc);
        qpacc = __builtin_fmaf(q8[2], wa.z, qpacc);
        qpacc = __builtin_fmaf(q8[3], wa.w, qpacc);
        qpacc = __builtin_fmaf(q8[4], wb.x, qpacc);
        qpacc = __builtin_fmaf(q8[5], wb.y, qpacc);
        qpacc = __builtin_fmaf(q8[6], wb.z, qpacc);
        qpacc = __builtin_fmaf(q8[7], wb.w, qpacc);
    }
    qpacc *= NA;                                   // qp' = c * (qp + b1)

    // w2c packed: wc' = w2[e] * (1/8)*log2e / c = w2[e] * -0.07344288
    u32 wcp[4][2];
    float w2row = w2[lane] * -0.07344288f;
#pragma unroll
    for (int mt = 0; mt < 4; ++mt)
#pragma unroll
        for (int h2 = 0; h2 < 2; ++h2) {
            int e0 = mt * 16 + hi * 4 + h2 * 2;
            u32 lo16 = (u32)f2b(__shfl(w2row, e0));
            u32 hi16 = (u32)f2b(__shfl(w2row, e0 + 1));
            wcp[mt][h2] = (hi16 << 16) | lo16;
        }

    // q pieces for frag build: qv2[ks][j] = q[ks*32 + hi*8 + j]
    float qv2[2][8];
#pragma unroll
    for (int ks = 0; ks < 2; ++ks)
#pragma unroll
        for (int j = 0; j < 8; ++j)
            qv2[ks][j] = q_l[wv * 64 + ks * 32 + hi * 8 + j];

    // A-frags: c * qw'[e = mt*16+lo][dd = ks*32 + hi*8 + j], bf16
    short8 af[4][2];
#pragma unroll
    for (int mt = 0; mt < 4; ++mt) {
        const float* wr = w1 + (mt * 16 + lo) * 192;
#pragma unroll
        for (int ks = 0; ks < 2; ++ks) {
            int dd0 = ks * 32 + hi * 8;
            float4 a0 = *(const float4*)(wr + 128 + dd0);
            float4 a1 = *(const float4*)(wr + 128 + dd0 + 4);
            float4 k0 = *(const float4*)(wr + 64 + dd0);
            float4 k1 = *(const float4*)(wr + 64 + dd0 + 4);
            union { u16 u[8]; short8 s; } cv;
            cv.u[0] = f2b(NA * __builtin_fmaf(qv2[ks][0], a0.x, k0.x));
            cv.u[1] = f2b(NA * __builtin_fmaf(qv2[ks][1], a0.y, k0.y));
            cv.u[2] = f2b(NA * __builtin_fmaf(qv2[ks][2], a0.z, k0.z));
            cv.u[3] = f2b(NA * __builtin_fmaf(qv2[ks][3], a0.w, k0.w));
            cv.u[4] = f2b(NA * __builtin_fmaf(qv2[ks][4], a1.x, k1.x));
            cv.u[5] = f2b(NA * __builtin_fmaf(qv2[ks][5], a1.y, k1.y));
            cv.u[6] = f2b(NA * __builtin_fmaf(qv2[ks][6], a1.z, k1.z));
            cv.u[7] = f2b(NA * __builtin_fmaf(qv2[ks][7], a1.w, k1.w));
            af[mt][ks] = cv.s;
        }
    }

    // rank-1 qp' C-init, loop-invariant
    floatx4 qpinit[4];
    {
        const floatx4 z = (floatx4){0.f, 0.f, 0.f, 0.f};
        union { u16 u[8]; short8 s; } bb;
#pragma unroll
        for (int i = 0; i < 8; ++i) bb.u[i] = 0;
        bb.u[0] = (hi == 0) ? (u16)0x3F80 : (u16)0;   // bf16 1.0 at k=0
#pragma unroll
        for (int mt = 0; mt < 4; ++mt) {
            float qpv = __shfl(qpacc, mt * 16 + lo);
            union { u16 u[8]; short8 s; } aa;
#pragma unroll
            for (int i = 0; i < 8; ++i) aa.u[i] = 0;
            aa.u[0] = (hi == 0) ? f2b(qpv) : (u16)0;
            qpinit[mt] = __builtin_amdgcn_mfma_f32_16x16x32_bf16(aa.s, bb.s, z, 0, 0, 0);
        }
    }

    // zero-init must complete block-wide before any wave's first p-write
    __syncthreads();

    float l_run = 0.f;
    floatx4 pvacc = (floatx4){0.f, 0.f, 0.f, 0.f};   // out[q=row 0..3][d = wv*16+col]
    const u16* kbase = kb + bh * 65536;
    // V^T B-frag bases: this wave's d-tile row = wv*16+lo, k-offset hi*8
    const u16* vhb = vthi + bh * 65536 + (wv * 16 + lo) * 1024 + hi * 8;
    const u16* vlb = vtlo + bh * 65536 + (wv * 16 + lo) * 1024 + hi * 8;

    // prologue: load B-frags for chunk j=0
    short8 bf[2][2];
#pragma unroll
    for (int t = 0; t < 2; ++t)
#pragma unroll
        for (int ks = 0; ks < 2; ++ks) {
            uint4 kv = *(const uint4*)(kbase + (t * 16 + lo) * 64 + ks * 32 + hi * 8);
            bf[t][ks] = *(short8*)&kv;
        }

    for (int g = 0; g < 8; ++g) {
        u16* gw = plds + (g & 1) * (4 * 528);      // this group's write buffer
#pragma unroll
        for (int c = 0; c < 4; ++c) {
            int jc = g * 128 + c * 32;                   // this chunk's key base (bf holds it)
            int jn = (jc + 32) & 1023;                   // next chunk to prefetch (wraps once, unused)

            float s0a = 0.f, s0b = 0.f, s1a = 0.f, s1b = 0.f;

            // pipeline prologue: mt=0's 4 MFMAs
            floatx4 aP[2], aN[2];
            aP[0] = __builtin_amdgcn_mfma_f32_16x16x32_bf16(af[0][0], bf[0][0], qpinit[0], 0, 0, 0);
            aP[0] = __builtin_amdgcn_mfma_f32_16x16x32_bf16(af[0][1], bf[0][1], aP[0], 0, 0, 0);
            aP[1] = __builtin_amdgcn_mfma_f32_16x16x32_bf16(af[0][0], bf[1][0], qpinit[0], 0, 0, 0);
            aP[1] = __builtin_amdgcn_mfma_f32_16x16x32_bf16(af[0][1], bf[1][1], aP[1], 0, 0, 0);

#pragma unroll
            for (int mt = 0; mt < 4; ++mt) {
                if (mt < 3) {
                    aN[0] = __builtin_amdgcn_mfma_f32_16x16x32_bf16(af[mt + 1][0], bf[0][0], qpinit[mt + 1], 0, 0, 0);
                    aN[0] = __builtin_amdgcn_mfma_f32_16x16x32_bf16(af[mt + 1][1], bf[0][1], aN[0], 0, 0, 0);
                    aN[1] = __builtin_amdgcn_mfma_f32_16x16x32_bf16(af[mt + 1][0], bf[1][0], qpinit[mt + 1], 0, 0, 0);
                    aN[1] = __builtin_amdgcn_mfma_f32_16x16x32_bf16(af[mt + 1][1], bf[1][1], aN[1], 0, 0, 0);
                } else {
                    // reload K frags in place for the next chunk
#pragma unroll
                    for (int t = 0; t < 2; ++t)
#pragma unroll
                        for (int ks = 0; ks < 2; ++ks) {
                            uint4 kv = *(const uint4*)(kbase + (jn + t * 16 + lo) * 64 + ks * 32 + hi * 8);
                            bf[t][ks] = *(short8*)&kv;
                        }
                }

                // score mt's pair: acc IS x' = c*hid; sigma via pair-merged rcp
#pragma unroll
                for (int h2 = 0; h2 < 2; ++h2) {
                    u32 wp = wcp[mt][h2];
                    float w0 = u2f(wp << 16);
                    float w1v = u2f(wp & 0xFFFF0000u);
#pragma unroll
                    for (int t = 0; t < 2; ++t) {
                        float x0 = aP[t][h2 * 2 + 0];
                        float x1 = aP[t][h2 * 2 + 1];
                        float a0 = 1.0f + __builtin_amdgcn_exp2f(x0);
                        float a1 = 1.0f + __builtin_amdgcn_exp2f(x1);
                        float rc = __builtin_amdgcn_rcpf(a0 * a1);
                        if (t == 0) {
                            s0a = __builtin_fmaf(x0 * w0,  rc * a1, s0a);
                            s0b = __builtin_fmaf(x1 * w1v, rc * a0, s0b);
                        } else {
                            s1a = __builtin_fmaf(x0 * w0,  rc * a1, s1a);
                            s1b = __builtin_fmaf(x1 * w1v, rc * a0, s1b);
                        }
                    }
                }
                aP[0] = aN[0];
                aP[1] = aN[1];
            }

            float s0 = s0a + s0b, s1 = s1a + s1b;
            s0 += __shfl_xor(s0, 16); s0 += __shfl_xor(s0, 32);   // s[j=lo]
            s1 += __shfl_xor(s1, 16); s1 += __shfl_xor(s1, 32);   // s[j=16+lo]

            // fixed-shift softmax numerator (scores bounded, safe)
            float p0 = __builtin_amdgcn_exp2f(s0 - 16.0f);
            float p1 = __builtin_amdgcn_exp2f(s1 - 16.0f);
            u16 ph0 = f2b(p0);
            u16 ph1 = f2b(p1);
            l_run += b2f(ph0) + b2f(ph1);              // l from QUANTIZED p

            // publish P for this chunk (fire-and-forget; drained at group barrier)
            u16* pw = gw + c * 528;
            if (lane < 16) {
                pw[((lo >> 3) * 16 + wv) * 8 + (lo & 7)] = ph0;            // j = lo
                pw[((2 + (lo >> 3)) * 16 + wv) * 8 + (lo & 7)] = ph1;      // j = 16+lo
            }
        }

        __syncthreads();

        // PV on the matrix pipe: out[q][d] += P[q][j] * (Vhi + Vlo)[d][j]
#pragma unroll
        for (int c = 0; c < 4; ++c) {
            int jg = g * 128 + c * 32;
            uint4 vh = *(const uint4*)(vhb + jg);
            uint4 vl = *(const uint4*)(vlb + jg);
            short8 pf = *(const short8*)(gw + c * 528 + lane * 8);
            pvacc = __builtin_amdgcn_mfma_f32_16x16x32_bf16(pf, *(short8*)&vh, pvacc, 0, 0, 0);
            pvacc = __builtin_amdgcn_mfma_f32_16x16x32_bf16(pf, *(short8*)&vl, pvacc, 0, 0, 0);
        }
    }

    float l = l_run;
    l += __shfl_xor(l, 1); l += __shfl_xor(l, 2);
    l += __shfl_xor(l, 4); l += __shfl_xor(l, 8);
    if (lane == 0) l_sh[wv] = l;
    __syncthreads();

    if (hi == 0) {                                 // C rows 0..3 live on lanes 0..15
        int b = bh >> 3, h = bh & 7;
#pragma unroll
        for (int q = 0; q < 4; ++q) {
            float outv = pvacc[q] * __builtin_amdgcn_rcpf(l_sh[q]);
            ao[((b * 1024 + qbase + q) * 512) + h * 64 + wv * 16 + lo] = outv;
        }
    }
}

// ---------------------------------------------------------------------------
extern "C" void kernel_launch(void* const* d_in, const int* in_sizes, int n_in,
                              void* d_out, int out_size, void* d_ws, size_t ws_size,
                              hipStream_t stream)
{
    (void)in_sizes; (void)n_in; (void)out_size; (void)ws_size;
    const float* x  = (const float*)d_in[0];
    const float* Wq = (const float*)d_in[1];
    const float* bq = (const float*)d_in[2];
    const float* Wk = (const float*)d_in[3];
    const float* bk = (const float*)d_in[4];
    const float* Wv = (const float*)d_in[5];
    const float* bv = (const float*)d_in[6];
    const float* w1 = (const float*)d_in[7];
    const float* b1 = (const float*)d_in[8];
    const float* w2 = (const float*)d_in[9];
    // d_in[10] = b2: scalar shift of all scores -> softmax-invariant -> unused
    const float* Wo = (const float*)d_in[11];
    const float* bo = (const float*)d_in[12];

    char* ws = (char*)d_ws;
    float* q_ws = (float*)(ws);               // 4 MB fp32 (b,h,c,d)
    u16*   k_ws = (u16*)(ws + (4u << 20));    // 2 MB bf16 (b,h,c,d)
    u16*   vthi = (u16*)(ws + (6u << 20));    // 2 MB bf16 V^T hi (b,h,d,c)
    u16*   vtlo = (u16*)(ws + (8u << 20));    // 2 MB bf16 V^T lo (b,h,d,c)
    float* a_ws = (float*)(ws + (10u << 20)); // 4 MB fp32 (b,c,D)

    dim3 blk(256);
    hipLaunchKernelGGL(gemm_qkv, dim3(32, 24), blk, 0, stream,
                       x, Wq, Wk, Wv, bq, bk, bv, q_ws, k_ws, vthi, vtlo);
    hipLaunchKernelGGL(attn17, dim3(4096), blk, 0, stream,
                       q_ws, k_ws, vthi, vtlo, w1, b1, w2, a_ws);
    hipLaunchKernelGGL(gemm_out, dim3(32, 8), blk, 0, stream, a_ws, Wo, bo, (float*)d_out);
}

// Round 6
// 553.230 us; speedup vs baseline: 2.1303x; 1.0099x over previous
//
#include <hip/hip_runtime.h>
#include <cstdint>

typedef unsigned short u16;
typedef unsigned int u32;
typedef __attribute__((ext_vector_type(8))) short short8;   // 8 bf16 (MFMA A/B frag)
typedef __attribute__((ext_vector_type(4))) float floatx4;  // MFMA C/D frag
typedef __attribute__((ext_vector_type(2))) float floatx2;  // packed f32 pair (v_pk_*_f32)

__device__ __forceinline__ float b2f(u16 u) {
    union { unsigned int i; float f; } c; c.i = ((unsigned int)u) << 16; return c.f;
}
__device__ __forceinline__ u16 f2b(float f) {
    union { float f; unsigned int i; } c; c.f = f;
    unsigned int u = c.i;
    u = u + 0x7FFFu + ((u >> 16) & 1u);   // RNE
    return (u16)(u >> 16);
}
__device__ __forceinline__ float u2f(u32 u) { union { u32 u; float f; } c; c.u = u; return c.f; }

// ---------------------------------------------------------------------------
// Fused Q/K/V projection GEMM. Y[m,n] = sum_k x[m,k]*W[n,k] + bias[n].
// grid (32, 24): which = blockIdx.y>>3 (0=q fp32, 1=k bf16, 2=v -> vt hi/lo bf16 transposed).
// ---------------------------------------------------------------------------
__global__ __launch_bounds__(256) void gemm_qkv(
    const float* __restrict__ x,
    const float* __restrict__ Wq, const float* __restrict__ Wk, const float* __restrict__ Wv,
    const float* __restrict__ bq, const float* __restrict__ bk, const float* __restrict__ bv,
    float* __restrict__ qout, u16* __restrict__ kout,
    u16* __restrict__ vthi, u16* __restrict__ vtlo)
{
    __shared__ u16 xs[64 * 72];
    __shared__ u16 wsl[64 * 72];
    int tid = threadIdx.x;
    int lane = tid & 63;
    int wv = tid >> 6;
    int lo = lane & 15, hi = lane >> 4;
    int which = blockIdx.y >> 3;
    int m0 = blockIdx.x * 64, n0 = (blockIdx.y & 7) * 64;
    const float* W    = which == 0 ? Wq : (which == 1 ? Wk : Wv);
    const float* bias = which == 0 ? bq : (which == 1 ? bk : bv);

    floatx4 acc[4];
#pragma unroll
    for (int mt = 0; mt < 4; ++mt) acc[mt] = (floatx4){0.f, 0.f, 0.f, 0.f};

    for (int k0 = 0; k0 < 512; k0 += 64) {
        __syncthreads();
#pragma unroll
        for (int i = 0; i < 2; ++i) {
            int v = tid + i * 256;
            int row = v >> 3, c8 = (v & 7) * 8;
            const float* ap = x + (m0 + row) * 512 + k0 + c8;
            const float* wp = W + (n0 + row) * 512 + k0 + c8;
            float4 a0 = *(const float4*)(ap);
            float4 a1 = *(const float4*)(ap + 4);
            float4 w0 = *(const float4*)(wp);
            float4 w1v = *(const float4*)(wp + 4);
            union { u16 u[8]; uint4 q; } ca, cw;
            ca.u[0] = f2b(a0.x); ca.u[1] = f2b(a0.y); ca.u[2] = f2b(a0.z); ca.u[3] = f2b(a0.w);
            ca.u[4] = f2b(a1.x); ca.u[5] = f2b(a1.y); ca.u[6] = f2b(a1.z); ca.u[7] = f2b(a1.w);
            cw.u[0] = f2b(w0.x); cw.u[1] = f2b(w0.y); cw.u[2] = f2b(w0.z); cw.u[3] = f2b(w0.w);
            cw.u[4] = f2b(w1v.x); cw.u[5] = f2b(w1v.y); cw.u[6] = f2b(w1v.z); cw.u[7] = f2b(w1v.w);
            *(uint4*)(xs + row * 72 + c8)  = ca.q;
            *(uint4*)(wsl + row * 72 + c8) = cw.q;
        }
        __syncthreads();
#pragma unroll
        for (int ks = 0; ks < 2; ++ks) {
            short8 bfr = *(const short8*)(wsl + (wv * 16 + lo) * 72 + ks * 32 + hi * 8);
#pragma unroll
            for (int mt = 0; mt < 4; ++mt) {
                short8 afr = *(const short8*)(xs + (mt * 16 + lo) * 72 + ks * 32 + hi * 8);
                acc[mt] = __builtin_amdgcn_mfma_f32_16x16x32_bf16(afr, bfr, acc[mt], 0, 0, 0);
            }
        }
    }

    int n = n0 + wv * 16 + lo;
    float bv2 = bias[n];
    if (which == 2) {
        // transpose V tile through LDS; emit vt_hi/vt_lo bf16 [bh][d][c]
        __syncthreads();                           // xs/wsl reuse: all waves done with MFMAs
        int nl = wv * 16 + lo;                     // local d
#pragma unroll
        for (int mt = 0; mt < 4; ++mt)
#pragma unroll
            for (int r = 0; r < 4; ++r) {
                int ml = mt * 16 + hi * 4 + r;     // local c
                float y = acc[mt][r] + bv2;
                u16 vh = f2b(y);
                u16 vl = f2b(y - b2f(vh));
                xs[nl * 72 + ml]  = vh;
                wsl[nl * 72 + ml] = vl;
            }
        __syncthreads();
        int row = tid >> 2, seg = (tid & 3) * 16;  // row = local d, seg = local c chunk
        int b = m0 >> 10, c0 = m0 & 1023, h2 = n0 >> 6;
        size_t dst = ((size_t)((b * 8 + h2) * 64 + row)) * 1024 + c0 + seg;
        *(uint4*)(vthi + dst)     = *(uint4*)(xs  + row * 72 + seg);
        *(uint4*)(vthi + dst + 8) = *(uint4*)(xs  + row * 72 + seg + 8);
        *(uint4*)(vtlo + dst)     = *(uint4*)(wsl + row * 72 + seg);
        *(uint4*)(vtlo + dst + 8) = *(uint4*)(wsl + row * 72 + seg + 8);
    } else {
        int h = n >> 6, dd = n & 63;
#pragma unroll
        for (int mt = 0; mt < 4; ++mt)
#pragma unroll
            for (int r = 0; r < 4; ++r) {
                int m = m0 + mt * 16 + hi * 4 + r;  // C/D: row=(lane>>4)*4+reg, col=lane&15
                float y = acc[mt][r] + bv2;
                int b = m >> 10, c = m & 1023;
                int idx = (((b * 8 + h) * 1024) + c) * 64 + dd;
                if (which == 0) qout[idx] = y;
                else            kout[idx] = f2b(y);
            }
    }
}

// ---------------------------------------------------------------------------
// Output GEMM: Y[m,n] = sum_k A[m,k]*Wo[n,k] + bo[n], fp32 out, [m*512+n].
// ---------------------------------------------------------------------------
__global__ __launch_bounds__(256) void gemm_out(
    const float* __restrict__ A, const float* __restrict__ W, const float* __restrict__ bias,
    float* __restrict__ outf)
{
    __shared__ u16 xs[64 * 72];
    __shared__ u16 wsl[64 * 72];
    int tid = threadIdx.x;
    int lane = tid & 63;
    int wv = tid >> 6;
    int lo = lane & 15, hi = lane >> 4;
    int m0 = blockIdx.x * 64, n0 = blockIdx.y * 64;

    floatx4 acc[4];
#pragma unroll
    for (int mt = 0; mt < 4; ++mt) acc[mt] = (floatx4){0.f, 0.f, 0.f, 0.f};

    for (int k0 = 0; k0 < 512; k0 += 64) {
        __syncthreads();
#pragma unroll
        for (int i = 0; i < 2; ++i) {
            int v = tid + i * 256;
            int row = v >> 3, c8 = (v & 7) * 8;
            const float* ap = A + (m0 + row) * 512 + k0 + c8;
            const float* wp = W + (n0 + row) * 512 + k0 + c8;
            float4 a0 = *(const float4*)(ap);
            float4 a1 = *(const float4*)(ap + 4);
            float4 w0 = *(const float4*)(wp);
            float4 w1v = *(const float4*)(wp + 4);
            union { u16 u[8]; uint4 q; } ca, cw;
            ca.u[0] = f2b(a0.x); ca.u[1] = f2b(a0.y); ca.u[2] = f2b(a0.z); ca.u[3] = f2b(a0.w);
            ca.u[4] = f2b(a1.x); ca.u[5] = f2b(a1.y); ca.u[6] = f2b(a1.z); ca.u[7] = f2b(a1.w);
            cw.u[0] = f2b(w0.x); cw.u[1] = f2b(w0.y); cw.u[2] = f2b(w0.z); cw.u[3] = f2b(w0.w);
            cw.u[4] = f2b(w1v.x); cw.u[5] = f2b(w1v.y); cw.u[6] = f2b(w1v.z); cw.u[7] = f2b(w1v.w);
            *(uint4*)(xs + row * 72 + c8)  = ca.q;
            *(uint4*)(wsl + row * 72 + c8) = cw.q;
        }
        __syncthreads();
#pragma unroll
        for (int ks = 0; ks < 2; ++ks) {
            short8 bfr = *(const short8*)(wsl + (wv * 16 + lo) * 72 + ks * 32 + hi * 8);
#pragma unroll
            for (int mt = 0; mt < 4; ++mt) {
                short8 afr = *(const short8*)(xs + (mt * 16 + lo) * 72 + ks * 32 + hi * 8);
                acc[mt] = __builtin_amdgcn_mfma_f32_16x16x32_bf16(afr, bfr, acc[mt], 0, 0, 0);
            }
        }
    }

    int n = n0 + wv * 16 + lo;
    float bv = bias[n];
#pragma unroll
    for (int mt = 0; mt < 4; ++mt)
#pragma unroll
        for (int r = 0; r < 4; ++r) {
            int m = m0 + mt * 16 + hi * 4 + r;
            outf[m * 512 + n] = acc[mt][r] + bv;
        }
}

// ---------------------------------------------------------------------------
// Fused second-order attention, v18 = v17 with VALU-issue diet (v17 PMC:
// VALUBusy 55% dominant, idle 30%, occupancy reg-capped at 4 waves/SIMD --
// so fewer VALU slots is the lever, schedule unchanged):
//  (1) packed-f32 scoring: per-pair sigmoid/score math in floatx2 so the
//      compiler emits v_pk_{add,mul,fma}_f32 -- 9 slots -> ~5 per pair.
//  (2) strength-reduced K addressing: one walking per-lane pointer +4096 B
//      per chunk; 4 reload loads at imm offsets {0,64,2048,2112} B. No &1023
//      wrap (final over-run load lands in workspace, value never consumed).
//  (3) V loads via walking pointer +256 B/group, imm offsets 0..192 B.
// ---------------------------------------------------------------------------
__global__ __launch_bounds__(256, 4) void attn18(
    const float* __restrict__ qf, const u16* __restrict__ kb,
    const u16* __restrict__ vthi, const u16* __restrict__ vtlo,
    const float* __restrict__ w1, const float* __restrict__ b1, const float* __restrict__ w2,
    float* __restrict__ ao)
{
    __shared__ float q_l[4 * 64];
    __shared__ __align__(16) u16 plds[2 * 4 * 528];   // [dbuf][chunk plane 528][A-frag order]
    __shared__ float l_sh[4];
    int tid = threadIdx.x;
    int lane = tid & 63;
    int wv = tid >> 6;
    int lo = lane & 15, hi = lane >> 4;
    int bh = blockIdx.x >> 8;                      // 0..15 = b*8+h
    int qbase = (blockIdx.x & 255) << 2;           // block's first query
    int qi = qbase | wv;                           // this wave's query

    const float NA = -2.45546696f;                 // -1.702 * log2(e)

    // zero p-LDS once: A-frag rows q=4..15 must stay 0 so PV C rows 4..15 are clean
    for (int i = tid; i < 2112; i += 256) ((u32*)plds)[i] = 0;

    q_l[wv * 64 + lane] = qf[(bh * 1024 + qi) * 64 + lane];

    // qp[e]+b1[e] at lane=e
    float qpacc = b1[lane];
#pragma unroll
    for (int d8 = 0; d8 < 64; d8 += 8) {
        float4 wa = *(const float4*)(w1 + lane * 192 + d8);
        float4 wb = *(const float4*)(w1 + lane * 192 + d8 + 4);
        const float* q8 = q_l + wv * 64 + d8;      // wave-uniform broadcast reads
        qpacc = __builtin_fmaf(q8[0], wa.x, qpacc);
        qpacc = __builtin_fmaf(q8[1], wa.y, qpacc);
        qpacc = __builtin_fmaf(q8[2], wa.z, qpacc);
        qpacc = __builtin_fmaf(q8[3], wa.w, qpacc);
        qpacc = __builtin_fmaf(q8[4], wb.x, qpacc);
        qpacc = __builtin_fmaf(q8[5], wb.y, qpacc);
        qpacc = __builtin_fmaf(q8[6], wb.z, qpacc);
        qpacc = __builtin_fmaf(q8[7], wb.w, qpacc);
    }
    qpacc *= NA;                                   // qp' = c * (qp + b1)

    // w2c packed: wc' = w2[e] * (1/8)*log2e / c = w2[e] * -0.07344288
    u32 wcp[4][2];
    float w2row = w2[lane] * -0.07344288f;
#pragma unroll
    for (int mt = 0; mt < 4; ++mt)
#pragma unroll
        for (int h2 = 0; h2 < 2; ++h2) {
            int e0 = mt * 16 + hi * 4 + h2 * 2;
            u32 lo16 = (u32)f2b(__shfl(w2row, e0));
            u32 hi16 = (u32)f2b(__shfl(w2row, e0 + 1));
            wcp[mt][h2] = (hi16 << 16) | lo16;
        }

    // q pieces for frag build: qv2[ks][j] = q[ks*32 + hi*8 + j]
    float qv2[2][8];
#pragma unroll
    for (int ks = 0; ks < 2; ++ks)
#pragma unroll
        for (int j = 0; j < 8; ++j)
            qv2[ks][j] = q_l[wv * 64 + ks * 32 + hi * 8 + j];

    // A-frags: c * qw'[e = mt*16+lo][dd = ks*32 + hi*8 + j], bf16
    short8 af[4][2];
#pragma unroll
    for (int mt = 0; mt < 4; ++mt) {
        const float* wr = w1 + (mt * 16 + lo) * 192;
#pragma unroll
        for (int ks = 0; ks < 2; ++ks) {
            int dd0 = ks * 32 + hi * 8;
            float4 a0 = *(const float4*)(wr + 128 + dd0);
            float4 a1 = *(const float4*)(wr + 128 + dd0 + 4);
            float4 k0 = *(const float4*)(wr + 64 + dd0);
            float4 k1 = *(const float4*)(wr + 64 + dd0 + 4);
            union { u16 u[8]; short8 s; } cv;
            cv.u[0] = f2b(NA * __builtin_fmaf(qv2[ks][0], a0.x, k0.x));
            cv.u[1] = f2b(NA * __builtin_fmaf(qv2[ks][1], a0.y, k0.y));
            cv.u[2] = f2b(NA * __builtin_fmaf(qv2[ks][2], a0.z, k0.z));
            cv.u[3] = f2b(NA * __builtin_fmaf(qv2[ks][3], a0.w, k0.w));
            cv.u[4] = f2b(NA * __builtin_fmaf(qv2[ks][4], a1.x, k1.x));
            cv.u[5] = f2b(NA * __builtin_fmaf(qv2[ks][5], a1.y, k1.y));
            cv.u[6] = f2b(NA * __builtin_fmaf(qv2[ks][6], a1.z, k1.z));
            cv.u[7] = f2b(NA * __builtin_fmaf(qv2[ks][7], a1.w, k1.w));
            af[mt][ks] = cv.s;
        }
    }

    // rank-1 qp' C-init, loop-invariant
    floatx4 qpinit[4];
    {
        const floatx4 z = (floatx4){0.f, 0.f, 0.f, 0.f};
        union { u16 u[8]; short8 s; } bb;
#pragma unroll
        for (int i = 0; i < 8; ++i) bb.u[i] = 0;
        bb.u[0] = (hi == 0) ? (u16)0x3F80 : (u16)0;   // bf16 1.0 at k=0
#pragma unroll
        for (int mt = 0; mt < 4; ++mt) {
            float qpv = __shfl(qpacc, mt * 16 + lo);
            union { u16 u[8]; short8 s; } aa;
#pragma unroll
            for (int i = 0; i < 8; ++i) aa.u[i] = 0;
            aa.u[0] = (hi == 0) ? f2b(qpv) : (u16)0;
            qpinit[mt] = __builtin_amdgcn_mfma_f32_16x16x32_bf16(aa.s, bb.s, z, 0, 0, 0);
        }
    }

    // zero-init must complete block-wide before any wave's first p-write
    __syncthreads();

    float l_run = 0.f;
    floatx4 pvacc = (floatx4){0.f, 0.f, 0.f, 0.f};   // out[q=row 0..3][d = wv*16+col]

    // walking per-lane K pointer: chunk base + lane part; advances 2048 u16/chunk.
    // loads at imm offsets {0, 32, 1024, 1056} u16 = {0,64,2048,2112} B.
    const u16* kc = kb + bh * 65536 + lo * 64 + hi * 8;
    // walking V^T pointers: this wave's d-tile row = wv*16+lo, k-offset hi*8;
    // advance 128 u16/group, loads at imm offsets {0,32,64,96} u16.
    const u16* vhp = vthi + bh * 65536 + (wv * 16 + lo) * 1024 + hi * 8;
    const u16* vlp = vtlo + bh * 65536 + (wv * 16 + lo) * 1024 + hi * 8;

    // prologue: load B-frags for chunk j=0
    short8 bf[2][2];
    {
        uint4 k00 = *(const uint4*)(kc);
        uint4 k01 = *(const uint4*)(kc + 32);
        uint4 k10 = *(const uint4*)(kc + 1024);
        uint4 k11 = *(const uint4*)(kc + 1056);
        bf[0][0] = *(short8*)&k00; bf[0][1] = *(short8*)&k01;
        bf[1][0] = *(short8*)&k10; bf[1][1] = *(short8*)&k11;
    }

    for (int g = 0; g < 8; ++g) {
        u16* gw = plds + (g & 1) * (4 * 528);      // this group's write buffer
#pragma unroll
        for (int c = 0; c < 4; ++c) {
            floatx2 s0v = (floatx2){0.f, 0.f};
            floatx2 s1v = (floatx2){0.f, 0.f};

            // pipeline prologue: mt=0's 4 MFMAs
            floatx4 aP[2], aN[2];
            aP[0] = __builtin_amdgcn_mfma_f32_16x16x32_bf16(af[0][0], bf[0][0], qpinit[0], 0, 0, 0);
            aP[0] = __builtin_amdgcn_mfma_f32_16x16x32_bf16(af[0][1], bf[0][1], aP[0], 0, 0, 0);
            aP[1] = __builtin_amdgcn_mfma_f32_16x16x32_bf16(af[0][0], bf[1][0], qpinit[0], 0, 0, 0);
            aP[1] = __builtin_amdgcn_mfma_f32_16x16x32_bf16(af[0][1], bf[1][1], aP[1], 0, 0, 0);

#pragma unroll
            for (int mt = 0; mt < 4; ++mt) {
                if (mt < 3) {
                    aN[0] = __builtin_amdgcn_mfma_f32_16x16x32_bf16(af[mt + 1][0], bf[0][0], qpinit[mt + 1], 0, 0, 0);
                    aN[0] = __builtin_amdgcn_mfma_f32_16x16x32_bf16(af[mt + 1][1], bf[0][1], aN[0], 0, 0, 0);
                    aN[1] = __builtin_amdgcn_mfma_f32_16x16x32_bf16(af[mt + 1][0], bf[1][0], qpinit[mt + 1], 0, 0, 0);
                    aN[1] = __builtin_amdgcn_mfma_f32_16x16x32_bf16(af[mt + 1][1], bf[1][1], aN[1], 0, 0, 0);
                } else {
                    // advance + reload K frags for the next chunk (final advance
                    // runs 4KB past this bh's K region: in-workspace, unused)
                    kc += 2048;
                    uint4 k00 = *(const uint4*)(kc);
                    uint4 k01 = *(const uint4*)(kc + 32);
                    uint4 k10 = *(const uint4*)(kc + 1024);
                    uint4 k11 = *(const uint4*)(kc + 1056);
                    bf[0][0] = *(short8*)&k00; bf[0][1] = *(short8*)&k01;
                    bf[1][0] = *(short8*)&k10; bf[1][1] = *(short8*)&k11;
                }

                // score mt's pair (packed f32): acc IS x' = c*hid
#pragma unroll
                for (int h2 = 0; h2 < 2; ++h2) {
                    u32 wp = wcp[mt][h2];
                    floatx2 wv2 = (floatx2){u2f(wp << 16), u2f(wp & 0xFFFF0000u)};
#pragma unroll
                    for (int t = 0; t < 2; ++t) {
                        floatx2 x = (floatx2){aP[t][h2 * 2 + 0], aP[t][h2 * 2 + 1]};
                        floatx2 ex = (floatx2){__builtin_amdgcn_exp2f(x.x),
                                               __builtin_amdgcn_exp2f(x.y)};
                        floatx2 a = ex + 1.0f;                       // pk_add
                        float rc = __builtin_amdgcn_rcpf(a.x * a.y);
                        floatx2 sw = (floatx2){a.y, a.x};
                        floatx2 contrib = (x * wv2) * (sw * rc);     // pk_mul x3 -> pk_fma
                        if (t == 0) s0v += contrib; else s1v += contrib;
                    }
                }
                aP[0] = aN[0];
                aP[1] = aN[1];
            }

            float s0 = s0v.x + s0v.y, s1 = s1v.x + s1v.y;
            s0 += __shfl_xor(s0, 16); s0 += __shfl_xor(s0, 32);   // s[j=lo]
            s1 += __shfl_xor(s1, 16); s1 += __shfl_xor(s1, 32);   // s[j=16+lo]

            // fixed-shift softmax numerator (scores bounded, safe)
            float p0 = __builtin_amdgcn_exp2f(s0 - 16.0f);
            float p1 = __builtin_amdgcn_exp2f(s1 - 16.0f);
            u16 ph0 = f2b(p0);
            u16 ph1 = f2b(p1);
            l_run += b2f(ph0) + b2f(ph1);              // l from QUANTIZED p

            // publish P for this chunk (fire-and-forget; drained at group barrier)
            u16* pw = gw + c * 528;
            if (lane < 16) {
                pw[((lo >> 3) * 16 + wv) * 8 + (lo & 7)] = ph0;            // j = lo
                pw[((2 + (lo >> 3)) * 16 + wv) * 8 + (lo & 7)] = ph1;      // j = 16+lo
            }
        }

        __syncthreads();

        // PV on the matrix pipe: out[q][d] += P[q][j] * (Vhi + Vlo)[d][j]
#pragma unroll
        for (int c = 0; c < 4; ++c) {
            uint4 vh = *(const uint4*)(vhp + c * 32);
            uint4 vl = *(const uint4*)(vlp + c * 32);
            short8 pf = *(const short8*)(gw + c * 528 + lane * 8);
            pvacc = __builtin_amdgcn_mfma_f32_16x16x32_bf16(pf, *(short8*)&vh, pvacc, 0, 0, 0);
            pvacc = __builtin_amdgcn_mfma_f32_16x16x32_bf16(pf, *(short8*)&vl, pvacc, 0, 0, 0);
        }
        vhp += 128;
        vlp += 128;
    }

    float l = l_run;
    l += __shfl_xor(l, 1); l += __shfl_xor(l, 2);
    l += __shfl_xor(l, 4); l += __shfl_xor(l, 8);
    if (lane == 0) l_sh[wv] = l;
    __syncthreads();

    if (hi == 0) {                                 // C rows 0..3 live on lanes 0..15
        int b = bh >> 3, h = bh & 7;
#pragma unroll
        for (int q = 0; q < 4; ++q) {
            float outv = pvacc[q] * __builtin_amdgcn_rcpf(l_sh[q]);
            ao[((b * 1024 + qbase + q) * 512) + h * 64 + wv * 16 + lo] = outv;
        }
    }
}

// ---------------------------------------------------------------------------
extern "C" void kernel_launch(void* const* d_in, const int* in_sizes, int n_in,
                              void* d_out, int out_size, void* d_ws, size_t ws_size,
                              hipStream_t stream)
{
    (void)in_sizes; (void)n_in; (void)out_size; (void)ws_size;
    const float* x  = (const float*)d_in[0];
    const float* Wq = (const float*)d_in[1];
    const float* bq = (const float*)d_in[2];
    const float* Wk = (const float*)d_in[3];
    const float* bk = (const float*)d_in[4];
    const float* Wv = (const float*)d_in[5];
    const float* bv = (const float*)d_in[6];
    const float* w1 = (const float*)d_in[7];
    const float* b1 = (const float*)d_in[8];
    const float* w2 = (const float*)d_in[9];
    // d_in[10] = b2: scalar shift of all scores -> softmax-invariant -> unused
    const float* Wo = (const float*)d_in[11];
    const float* bo = (const float*)d_in[12];

    char* ws = (char*)d_ws;
    float* q_ws = (float*)(ws);               // 4 MB fp32 (b,h,c,d)
    u16*   k_ws = (u16*)(ws + (4u << 20));    // 2 MB bf16 (b,h,c,d)
    u16*   vthi = (u16*)(ws + (6u << 20));    // 2 MB bf16 V^T hi (b,h,d,c)
    u16*   vtlo = (u16*)(ws + (8u << 20));    // 2 MB bf16 V^T lo (b,h,d,c)
    float* a_ws = (float*)(ws + (10u << 20)); // 4 MB fp32 (b,c,D)

    dim3 blk(256);
    hipLaunchKernelGGL(gemm_qkv, dim3(32, 24), blk, 0, stream,
                       x, Wq, Wk, Wv, bq, bk, bv, q_ws, k_ws, vthi, vtlo);
    hipLaunchKernelGGL(attn18, dim3(4096), blk, 0, stream,
                       q_ws, k_ws, vthi, vtlo, w1, b1, w2, a_ws);
    hipLaunchKernelGGL(gemm_out, dim3(32, 8), blk, 0, stream, a_ws, Wo, bo, (float*)d_out);
}